// Round 6
// baseline (66.248 us; speedup 1.0000x reference)
//
#include <hip/hip_runtime.h>
#include <math.h>

#define MAXP 32

__device__ __forceinline__ float rdlanef(float v, int l) {
    return __int_as_float(__builtin_amdgcn_readlane(__float_as_int(v), l));
}
template <int CTRL>
__device__ __forceinline__ float dppadd(float v) {
    int t = __builtin_amdgcn_update_dpp(0, __float_as_int(v), CTRL, 0xF, 0xF, false);
    return v + __int_as_float(t);
}
// sum across each 16-lane group (partials become subgroup-uniform at each step)
__device__ __forceinline__ float sum16(float v) {
    v = dppadd<0xB1>(v);    // quad_perm(1,0,3,2)  == xor1
    v = dppadd<0x4E>(v);    // quad_perm(2,3,0,1)  == xor2
    v = dppadd<0x141>(v);   // row_half_mirror (i^7) == xor4 once quad-uniform
    v = dppadd<0x140>(v);   // row_mirror (i^15)     == xor8 once 8-uniform
    return v;
}

// one point: 4 FMA + 1 max (no masking)
#define PT(qq, mm) do {                                   \
    float v_ = fmaf((qq).x, A, E2);                       \
    v_ = fmaf((qq).y, B, v_);                             \
    v_ = fmaf((qq).z, C, v_);                             \
    v_ = fmaf((qq).w, Dk, v_);                            \
    mm = fmaxf(mm, v_);                                   \
} while (0)

__global__ __launch_bounds__(256, 8) void pfn_kernel(
    const float* __restrict__ voxels,
    const int*   __restrict__ num_points,
    const int*   __restrict__ coords,
    const float* __restrict__ W,
    const float* __restrict__ gammav,
    const float* __restrict__ betav,
    const float* __restrict__ rmean,
    const float* __restrict__ rvar,
    float*       __restrict__ out,
    int N)
{
    const int lane = threadIdx.x & 63;
    const int wid  = threadIdx.x >> 6;
    const int d    = lane;

    // ---- per-lane channel constants (amortized over 4 pillars) ----
    const float w0 = W[0*64+d], w1 = W[1*64+d], w2 = W[2*64+d];
    const float w3 = W[3*64+d], w4 = W[4*64+d], w5 = W[5*64+d];
    const float w6 = W[6*64+d], w7 = W[7*64+d], w8 = W[8*64+d];
    const float inv   = gammav[d] * rsqrtf(rvar[d] + 1e-3f);
    const float shift = fmaf(-rmean[d], inv, betav[d]);
    const float A  = (w0 + w4 + w7) * inv;
    const float B  = (w1 + w5 + w8) * inv;
    const float C  = (w2 + w6) * inv;
    const float Dk = w3 * inv;
    const float P4 = w4*inv, P5 = w5*inv, P6 = w6*inv, P7 = w7*inv, P8 = w8*inv;

    int vzero;                       // opaque 0: forces VMEM (not SMEM) addressing
    asm("v_mov_b32 %0, 0" : "=v"(vzero));

    const int base = blockIdx.x * 16 + wid * 4;   // 4 pillars per wave
    if (base >= N) return;

    // ---- batched scalar loads for 4 pillars (uniform -> s_load, hoisted) ----
    const int s0 = min(base + 0, N - 1), s1 = min(base + 1, N - 1);
    const int s2 = min(base + 2, N - 1), s3 = min(base + 3, N - 1);
    const int np0 = num_points[s0], np1 = num_points[s1];
    const int np2 = num_points[s2], np3 = num_points[s3];
    const int cx0 = coords[s0*3], cy0 = coords[s0*3+1];
    const int cx1 = coords[s1*3], cy1 = coords[s1*3+1];
    const int cx2 = coords[s2*3], cy2 = coords[s2*3+1];
    const int cx3 = coords[s3*3], cy3 = coords[s3*3+1];

    // ---- phase A: coalesced per-lane loads; xyz sums over ALL 32 pts via DPP ----
    const int pl = lane >> 4;                  // pillar_local 0..3
    const int ch = lane & 15;                  // 2 points per lane
    const int pA = min(base + pl, N - 1);
    const float4* pa = (const float4*)(voxels + (size_t)pA * 128) + ch * 2;
    const float4 f0 = pa[0], f1 = pa[1];
    const float bx = sum16(f0.x + f1.x);
    const float by = sum16(f0.y + f1.y);
    const float bz = sum16(f0.z + f1.z);

    auto pillarBody = [&](int sp, bool ok, int np, int cxi, int cyi,
                          float sx, float sy, float sz) {
        const float cxf = fmaf((float)cxi, 0.2f, 0.1f);    // VX/2 + 0
        const float cyf = fmaf((float)cyi, 0.2f, -25.5f);  // VY/2 - 25.6
        const float E2  = shift - cxf*P7 - cyf*P8;         // mean term deferred

        const float4* bp = (const float4*)(voxels + (size_t)sp * 128) + vzero;

        float m0 = -INFINITY, m1 = -INFINITY;
        const int full = np >> 2;              // complete 4-point windows
        #pragma unroll 1
        for (int w = 0; w < full; ++w) {       // uniform trip count, no masking
            const float4* q = bp + (w << 2);
            float4 a0 = q[0], a1 = q[1], a2 = q[2], a3 = q[3];
            PT(a0, m0); PT(a1, m1); PT(a2, m0); PT(a3, m1);
        }
        const int rem = np & 3;
        if (rem) {                              // uniform branch; <=3 points
            const float4* q = bp + (full << 2); // indices <= 30: always in-bounds
            float4 a0 = q[0], a1 = q[1], a2 = q[2];
            float v0 = fmaf(a0.x, A, E2); v0 = fmaf(a0.y, B, v0);
            v0 = fmaf(a0.z, C, v0); v0 = fmaf(a0.w, Dk, v0);
            m0 = fmaxf(m0, v0);                 // rem >= 1
            float v1 = fmaf(a1.x, A, E2); v1 = fmaf(a1.y, B, v1);
            v1 = fmaf(a1.z, C, v1); v1 = fmaf(a1.w, Dk, v1);
            m1 = fmaxf(m1, (rem > 1) ? v1 : -INFINITY);
            float v2 = fmaf(a2.x, A, E2); v2 = fmaf(a2.y, B, v2);
            v2 = fmaf(a2.z, C, v2); v2 = fmaf(a2.w, Dk, v2);
            m0 = fmaxf(m0, (rem > 2) ? v2 : -INFINITY);
        }

        // deferred mean term: max_p(v_p) - S  ==  max_p(v_p - S)
        const float S = fmaf(sx, P4, fmaf(sy, P5, sz * P6)) *
                        __builtin_amdgcn_rcpf((float)np);
        float mf = fmaxf(m0, m1) - S;
        if (np < MAXP) mf = fmaxf(mf, shift);   // padded points contribute `shift`
        if (ok) out[(size_t)sp * 64 + d] = fmaxf(mf, 0.0f);
    };

    pillarBody(s0, base + 0 < N, np0, cx0, cy0,
               rdlanef(bx,  0), rdlanef(by,  0), rdlanef(bz,  0));
    pillarBody(s1, base + 1 < N, np1, cx1, cy1,
               rdlanef(bx, 16), rdlanef(by, 16), rdlanef(bz, 16));
    pillarBody(s2, base + 2 < N, np2, cx2, cy2,
               rdlanef(bx, 32), rdlanef(by, 32), rdlanef(bz, 32));
    pillarBody(s3, base + 3 < N, np3, cx3, cy3,
               rdlanef(bx, 48), rdlanef(by, 48), rdlanef(bz, 48));
}

extern "C" void kernel_launch(void* const* d_in, const int* in_sizes, int n_in,
                              void* d_out, int out_size, void* d_ws, size_t ws_size,
                              hipStream_t stream) {
    const float* voxels     = (const float*)d_in[0];
    const int*   num_points = (const int*)  d_in[1];
    const int*   coords     = (const int*)  d_in[2];
    const float* W          = (const float*)d_in[3];
    const float* gammav     = (const float*)d_in[4];
    const float* betav      = (const float*)d_in[5];
    const float* rmean      = (const float*)d_in[6];
    const float* rvar       = (const float*)d_in[7];
    float*       out        = (float*)d_out;

    const int N = in_sizes[1];                 // one entry per pillar
    const int blocks = (N + 15) / 16;          // 16 pillars per 256-thr block
    pfn_kernel<<<blocks, 256, 0, stream>>>(voxels, num_points, coords, W,
                                           gammav, betav, rmean, rvar, out, N);
}